// Round 5
// baseline (1298.199 us; speedup 1.0000x reference)
//
#include <hip/hip_runtime.h>
#include <stdint.h>

// Sparse top-k attention (B=4,N=2048,H=16,DH=64, topk=64).
// Selection matches numpy f32: q32/k32 ~f32-exact (6-term 3-word-split MFMA);
// bulk scores 3-term 2-word MFMA stored f16 (|err| <= DELTA); 10-step value
// bisection; boundary candidates recomputed from q32/k32 (f64 accum) and
// ranked exactly, with numpy tie semantics (score == vk kept). v in f16.
// attn_k processes its wave's TWO rows fused (2x ILP); Kt/S/qE XOR-swizzled.

typedef __attribute__((ext_vector_type(8))) short short8;
typedef __attribute__((ext_vector_type(4))) float floatx4;

#define Bn   4
#define Nn   2048
#define Hn   16
#define BHn  (Bn*Hn)
#define DELTA 0.00125f

__device__ __forceinline__ float bf2f(unsigned short u) {
  union { unsigned int i; float f; } v; v.i = ((unsigned int)u) << 16; return v.f;
}
__device__ __forceinline__ unsigned short f2bf(float f) {
  union { float f; unsigned int i; } v; v.f = f;
  unsigned int r = v.i + 0x7fffu + ((v.i >> 16) & 1u);
  return (unsigned short)(r >> 16);
}
__device__ __forceinline__ floatx4 mfma16(short8 a, short8 b, floatx4 c) {
  return __builtin_amdgcn_mfma_f32_16x16x32_bf16(a, b, c, 0, 0, 0);
}
__device__ __forceinline__ void split2(float x, unsigned short& h, unsigned short& m) {
  h = f2bf(x);
  m = f2bf(x - bf2f(h));
}
__device__ __forceinline__ void split3(float x, unsigned short& h, unsigned short& m, unsigned short& l) {
  h = f2bf(x);
  float r = x - bf2f(h);
  m = f2bf(r);
  l = f2bf(r - bf2f(m));
}

// ---- W[K][N] f32 -> T0/T1/T2[N][K] bf16 3-word split
__global__ __launch_bounds__(256)
void transpose_split3(const float* __restrict__ W,
                      unsigned short* __restrict__ T0,
                      unsigned short* __restrict__ T1,
                      unsigned short* __restrict__ T2,
                      int K, int Ncols)
{
  __shared__ float tile[32][33];
  int k0 = blockIdx.y * 32, n0 = blockIdx.x * 32;
  int tx = threadIdx.x & 31, ty = threadIdx.x >> 5;
  for (int s = 0; s < 32; s += 8)
    tile[ty + s][tx] = W[(size_t)(k0 + ty + s) * Ncols + n0 + tx];
  __syncthreads();
  for (int s = 0; s < 32; s += 8) {
    float x = tile[tx][ty + s];
    unsigned short h, m, l;
    split3(x, h, m, l);
    size_t o = (size_t)(n0 + ty + s) * K + k0 + tx;
    T0[o] = h; T1[o] = m; T2[o] = l;
  }
}

// ---- W[K][N] f32 -> T0/T1[N][K] bf16 2-word split
__global__ __launch_bounds__(256)
void transpose_split2(const float* __restrict__ W,
                      unsigned short* __restrict__ T0,
                      unsigned short* __restrict__ T1,
                      int K, int Ncols)
{
  __shared__ float tile[32][33];
  int k0 = blockIdx.y * 32, n0 = blockIdx.x * 32;
  int tx = threadIdx.x & 31, ty = threadIdx.x >> 5;
  for (int s = 0; s < 32; s += 8)
    tile[ty + s][tx] = W[(size_t)(k0 + ty + s) * Ncols + n0 + tx];
  __syncthreads();
  for (int s = 0; s < 32; s += 8) {
    float x = tile[tx][ty + s];
    unsigned short h, m;
    split2(x, h, m);
    size_t o = (size_t)(n0 + ty + s) * K + k0 + tx;
    T0[o] = h; T1[o] = m;
  }
}

__global__ __launch_bounds__(256)
void convert_bf16(const float* __restrict__ in, unsigned short* __restrict__ outp, int n) {
  int i = blockIdx.x * 256 + threadIdx.x;
  if (i < n) outp[i] = f2bf(in[i]);
}

// ---- QKV GEMM: A(f32) split3 on the fly, B 3-word. q/k tiles: 6 MFMA terms
// (~f32-exact), outputs f32 + 2-word bf16. Pure-V tiles (n0>=1024): 3 terms,
// f16 output.
__global__ __launch_bounds__(256)
void gemm_qkv(const float* __restrict__ A,
              const unsigned short* __restrict__ B0,
              const unsigned short* __restrict__ B1,
              const unsigned short* __restrict__ B2,
              const float* __restrict__ bias,
              float* __restrict__ O32,
              unsigned short* __restrict__ Oh,
              unsigned short* __restrict__ Om,
              _Float16* __restrict__ Vh,
              int K, float scale)
{
  __shared__ unsigned short lA[3][128 * 40];
  __shared__ unsigned short lB[3][128 * 40];
  const int tid = threadIdx.x;
  const int lane = tid & 63;
  const int m0 = blockIdx.y * 128, n0 = blockIdx.x * 128;
  const bool vblk = (n0 >= 1024);
  const int wid = tid >> 6, wm = wid >> 1, wn = wid & 1;
  const int fr = lane & 15, fq = lane >> 4;
  floatx4 acc[4][4] = {};

  for (int k0 = 0; k0 < K; k0 += 32) {
    __syncthreads();
    #pragma unroll
    for (int p = 0; p < 2; p++) {
      int c = tid + p * 256;
      int row = c >> 2, kc = (c & 3) * 8;
      size_t go = (size_t)(m0 + row) * K + k0 + kc;
      float4 v0 = *(const float4*)&A[go];
      float4 v1 = *(const float4*)&A[go + 4];
      union { unsigned short u[8]; uint4 q; } hh, mm, ll;
      float xs[8] = {v0.x, v0.y, v0.z, v0.w, v1.x, v1.y, v1.z, v1.w};
      #pragma unroll
      for (int e = 0; e < 8; e++) split3(xs[e], hh.u[e], mm.u[e], ll.u[e]);
      *(uint4*)&lA[0][row * 40 + kc] = hh.q;
      *(uint4*)&lA[1][row * 40 + kc] = mm.q;
      size_t bo = (size_t)(n0 + row) * K + k0 + kc;
      *(uint4*)&lB[0][row * 40 + kc] = *(const uint4*)&B0[bo];
      *(uint4*)&lB[1][row * 40 + kc] = *(const uint4*)&B1[bo];
      if (!vblk) {
        *(uint4*)&lA[2][row * 40 + kc] = ll.q;
        *(uint4*)&lB[2][row * 40 + kc] = *(const uint4*)&B2[bo];
      }
    }
    __syncthreads();
    short8 af0[4], af1[4], af2[4], bf0[4], bf1[4], bf2v[4];
    #pragma unroll
    for (int t = 0; t < 4; t++) {
      int ao = (wm * 64 + t * 16 + fr) * 40 + 8 * fq;
      int bo2 = (wn * 64 + t * 16 + fr) * 40 + 8 * fq;
      af0[t] = *(const short8*)&lA[0][ao];
      af1[t] = *(const short8*)&lA[1][ao];
      bf0[t] = *(const short8*)&lB[0][bo2];
      bf1[t] = *(const short8*)&lB[1][bo2];
      if (!vblk) {
        af2[t] = *(const short8*)&lA[2][ao];
        bf2v[t] = *(const short8*)&lB[2][bo2];
      }
    }
    #pragma unroll
    for (int mi = 0; mi < 4; mi++)
      #pragma unroll
      for (int ni = 0; ni < 4; ni++) {
        acc[mi][ni] = mfma16(af0[mi], bf0[ni], acc[mi][ni]);
        acc[mi][ni] = mfma16(af0[mi], bf1[ni], acc[mi][ni]);
        acc[mi][ni] = mfma16(af1[mi], bf0[ni], acc[mi][ni]);
        if (!vblk) {
          acc[mi][ni] = mfma16(af1[mi], bf1[ni], acc[mi][ni]);
          acc[mi][ni] = mfma16(af0[mi], bf2v[ni], acc[mi][ni]);
          acc[mi][ni] = mfma16(af2[mi], bf0[ni], acc[mi][ni]);
        }
      }
  }
  // C/D frag: row=(lane>>4)*4+rg, col=lane&15
  #pragma unroll
  for (int mi = 0; mi < 4; mi++)
    #pragma unroll
    for (int ni = 0; ni < 4; ni++) {
      int nl = n0 + wn * 64 + ni * 16 + fr;
      float bv = bias[nl];
      #pragma unroll
      for (int rg = 0; rg < 4; rg++) {
        int ml = m0 + wm * 64 + mi * 16 + fq * 4 + rg;
        float val = (acc[mi][ni][rg] + bv) * scale;
        int bb = ml >> 11, ii = ml & 2047;
        int hh2 = (nl & 1023) >> 6, dd = nl & 63;
        size_t idx = (((size_t)bb * Hn + hh2) * Nn + ii) * 64 + dd;
        if (!vblk) {
          O32[idx] = val;
          unsigned short h, m;
          split2(val, h, m);
          Oh[idx] = h; Om[idx] = m;
        } else {
          Vh[idx] = (_Float16)val;
        }
      }
    }
}

// ---- output GEMM: A f32 split2, B 2-word, 3 terms, f32 out.
__global__ __launch_bounds__(256)
void gemm_out(const float* __restrict__ A,
              const unsigned short* __restrict__ B0,
              const unsigned short* __restrict__ B1,
              const float* __restrict__ bias,
              float* __restrict__ O32,
              int Ncols, int K)
{
  __shared__ unsigned short lA[2][128 * 40];
  __shared__ unsigned short lB[2][128 * 40];
  const int tid = threadIdx.x;
  const int lane = tid & 63;
  const int m0 = blockIdx.y * 128, n0 = blockIdx.x * 128;
  const int wid = tid >> 6, wm = wid >> 1, wn = wid & 1;
  const int fr = lane & 15, fq = lane >> 4;
  floatx4 acc[4][4] = {};

  for (int k0 = 0; k0 < K; k0 += 32) {
    __syncthreads();
    #pragma unroll
    for (int p = 0; p < 2; p++) {
      int c = tid + p * 256;
      int row = c >> 2, kc = (c & 3) * 8;
      size_t go = (size_t)(m0 + row) * K + k0 + kc;
      float4 v0 = *(const float4*)&A[go];
      float4 v1 = *(const float4*)&A[go + 4];
      union { unsigned short u[8]; uint4 q; } hh, mm;
      float xs[8] = {v0.x, v0.y, v0.z, v0.w, v1.x, v1.y, v1.z, v1.w};
      #pragma unroll
      for (int e = 0; e < 8; e++) split2(xs[e], hh.u[e], mm.u[e]);
      *(uint4*)&lA[0][row * 40 + kc] = hh.q;
      *(uint4*)&lA[1][row * 40 + kc] = mm.q;
      size_t bo = (size_t)(n0 + row) * K + k0 + kc;
      *(uint4*)&lB[0][row * 40 + kc] = *(const uint4*)&B0[bo];
      *(uint4*)&lB[1][row * 40 + kc] = *(const uint4*)&B1[bo];
    }
    __syncthreads();
    short8 af[2][4], bfr[2][4];
    #pragma unroll
    for (int s = 0; s < 2; s++)
      #pragma unroll
      for (int t = 0; t < 4; t++) {
        af[s][t]  = *(const short8*)&lA[s][(wm * 64 + t * 16 + fr) * 40 + 8 * fq];
        bfr[s][t] = *(const short8*)&lB[s][(wn * 64 + t * 16 + fr) * 40 + 8 * fq];
      }
    #pragma unroll
    for (int mi = 0; mi < 4; mi++)
      #pragma unroll
      for (int ni = 0; ni < 4; ni++) {
        acc[mi][ni] = mfma16(af[0][mi], bfr[0][ni], acc[mi][ni]);
        acc[mi][ni] = mfma16(af[0][mi], bfr[1][ni], acc[mi][ni]);
        acc[mi][ni] = mfma16(af[1][mi], bfr[0][ni], acc[mi][ni]);
      }
  }
  #pragma unroll
  for (int mi = 0; mi < 4; mi++)
    #pragma unroll
    for (int ni = 0; ni < 4; ni++) {
      int nl = n0 + wn * 64 + ni * 16 + fr;
      float bv = bias[nl];
      #pragma unroll
      for (int rg = 0; rg < 4; rg++) {
        int ml = m0 + wm * 64 + mi * 16 + fq * 4 + rg;
        O32[(size_t)ml * Ncols + nl] = acc[mi][ni][rg] + bv;
      }
    }
}

// ---- attention: one WG (8 waves) = 16 query rows; each wave owns rows
// 2w,2w+1 processed FUSED. S/qE column-swizzled by (row>>2)<<4; Kt
// chunk-swizzled by row&7.
__global__ __launch_bounds__(512, 4)
void attn_k(const unsigned short* __restrict__ qh,
            const unsigned short* __restrict__ qm,
            const unsigned short* __restrict__ kh,
            const unsigned short* __restrict__ km,
            const _Float16* __restrict__ vh,
            const float* __restrict__ q32,
            const float* __restrict__ k32,
            const unsigned short* __restrict__ relbf,
            const float* __restrict__ rel32,
            const float* __restrict__ gating,
            const int* __restrict__ topkp,
            float* __restrict__ inner)
{
  extern __shared__ char smem[];
  _Float16* S = (_Float16*)smem;                          // [16][2048] 65536B
  unsigned short* KtH = (unsigned short*)(smem + 65536);  // [64][64] 8192B
  unsigned short* KtM = KtH + 4096;                       // [64][64] 8192B
  _Float16* qE = (_Float16*)KtH;                          // [16][256] reuse

  const int ib = blockIdx.x, bh = blockIdx.y;
  const int i0 = ib * 16;
  const int b = bh >> 4, h = bh & 15;
  const int tid = threadIdx.x;
  const int lane = tid & 63, w = tid >> 6;
  const int fr = lane & 15, fq = lane >> 4;
  const int topk = topkp[0];

  // q A-fragments, 2-word
  const size_t qoff = ((size_t)bh * Nn + i0) * 64;
  const size_t qf = qoff + (size_t)fr * 64 + 8 * fq;
  const short8 aqh0 = *(const short8*)&qh[qf];
  const short8 aqh1 = *(const short8*)&qh[qf + 32];
  const short8 aqm0 = *(const short8*)&qm[qf];
  const short8 aqm1 = *(const short8*)&qm[qf + 32];

  // QK^T: 32 tiles of 64 cols; waves 0-3 even tiles, 4-7 odd
  for (int jt = 0; jt < 32; jt++) {
    __syncthreads();
    {
      int row = tid >> 3, ch = tid & 7;
      int dst = row * 64 + ((ch ^ (row & 7)) * 8);   // chunk swizzle
      size_t g = ((size_t)bh * Nn + jt * 64 + row) * 64 + ch * 8;
      *(uint4*)&KtH[dst] = *(const uint4*)&kh[g];
      *(uint4*)&KtM[dst] = *(const uint4*)&km[g];
    }
    __syncthreads();
    if ((jt & 1) == (w >> 2)) {
      int wc = w & 3;
      int row16 = wc * 16 + fr, r7 = fr & 7;
      int b0 = row16 * 64 + ((fq ^ r7) * 8);
      int b1 = row16 * 64 + (((fq + 4) ^ r7) * 8);
      short8 kh0 = *(const short8*)&KtH[b0];
      short8 kh1 = *(const short8*)&KtH[b1];
      short8 km0 = *(const short8*)&KtM[b0];
      short8 km1 = *(const short8*)&KtM[b1];
      floatx4 c = {};
      c = mfma16(aqh0, kh0, c); c = mfma16(aqh1, kh1, c);
      c = mfma16(aqh0, km0, c); c = mfma16(aqh1, km1, c);
      c = mfma16(aqm0, kh0, c); c = mfma16(aqm1, kh1, c);
      int colsw = jt * 64 + ((wc ^ fq) * 16) + fr;   // col ^ (fq<<4)
      #pragma unroll
      for (int rg = 0; rg < 4; rg++)
        S[(fq * 4 + rg) * 2048 + colsw] = (_Float16)c[rg];
    }
  }
  __syncthreads();

  // qE[i_local][r] = q_i . rel_r (KtH region free now)
  #pragma unroll
  for (int rs = 0; rs < 2; rs++) {
    int rq = w * 2 + rs;
    size_t rf = (size_t)(rq * 16 + fr) * 64 + 8 * fq;
    short8 rb0 = *(const short8*)&relbf[rf];
    short8 rb1 = *(const short8*)&relbf[rf + 32];
    floatx4 c = {};
    c = mfma16(aqh0, rb0, c); c = mfma16(aqh1, rb1, c);
    c = mfma16(aqm0, rb0, c); c = mfma16(aqm1, rb1, c);
    int colsw = ((rq ^ fq) * 16) + fr;
    #pragma unroll
    for (int rg = 0; rg < 4; rg++)
      qE[(fq * 4 + rg) * 256 + colsw] = (_Float16)c[rg];
  }
  __syncthreads();

  // ---- fused two-row selection + softmax + PV
  const int r0 = w * 2, r1 = r0 + 1;
  const int ii0 = i0 + r0, ii1 = i0 + r1;
  const int X = (w >> 1) << 4;                       // (row>>2)<<4, same pair
  _Float16* S0 = S + r0 * 2048;
  _Float16* S1 = S + r1 * 2048;
  const _Float16* qE0 = qE + r0 * 256;
  const _Float16* qE1 = qE + r1 * 256;
  const float cA0 = (float)qE0[255 ^ X], cC0 = (float)qE0[X];
  const float cA1 = (float)qE1[255 ^ X], cC1 = (float)qE1[X];
  const int swl = (2 * lane) ^ X;

  float k0v[32], k1v[32];
  float mx0 = -3.0e38f, mx1 = -3.0e38f;
  float sm0 = 0.f, sm1 = 0.f, sq0 = 0.f, sq1 = 0.f;
  #pragma unroll
  for (int e = 0; e < 16; e++) {
    const int jb = 128 * e;
    union { unsigned int u; _Float16 hx[2]; } u0, u1;
    u0.u = *(const unsigned int*)&S0[jb + swl];
    u1.u = *(const unsigned int*)&S1[jb + swl];
    const int j0 = jb + 2 * lane;
    float e00, e01, e10, e11;
    if (jb + 127 <= ii0) { e00 = cA0; e01 = cA0; }
    else if (jb >= ii0 + 256) { e00 = cC0; e01 = cC0; }
    else {
      int c0 = ii0 - j0 + 256; c0 = c0 < 0 ? 0 : (c0 > 255 ? 255 : c0);
      int c1 = ii0 - j0 + 255; c1 = c1 < 0 ? 0 : (c1 > 255 ? 255 : c1);
      e00 = (float)qE0[c0 ^ X]; e01 = (float)qE0[c1 ^ X];
    }
    if (jb + 127 <= ii1) { e10 = cA1; e11 = cA1; }
    else if (jb >= ii1 + 256) { e10 = cC1; e11 = cC1; }
    else {
      int c0 = ii1 - j0 + 256; c0 = c0 < 0 ? 0 : (c0 > 255 ? 255 : c0);
      int c1 = ii1 - j0 + 255; c1 = c1 < 0 ? 0 : (c1 > 255 ? 255 : c1);
      e10 = (float)qE1[c0 ^ X]; e11 = (float)qE1[c1 ^ X];
    }
    float a0 = (float)u0.hx[0] + e00, a1 = (float)u0.hx[1] + e01;
    float b0 = (float)u1.hx[0] + e10, b1 = (float)u1.hx[1] + e11;
    k0v[2 * e] = a0; k0v[2 * e + 1] = a1;
    k1v[2 * e] = b0; k1v[2 * e + 1] = b1;
    mx0 = fmaxf(mx0, fmaxf(a0, a1)); mx1 = fmaxf(mx1, fmaxf(b0, b1));
    sm0 += a0 + a1; sm1 += b0 + b1;
    sq0 = fmaf(a0, a0, fmaf(a1, a1, sq0));
    sq1 = fmaf(b0, b0, fmaf(b1, b1, sq1));
  }
  #pragma unroll
  for (int d = 1; d < 64; d <<= 1) {
    mx0 = fmaxf(mx0, __shfl_xor(mx0, d));
    mx1 = fmaxf(mx1, __shfl_xor(mx1, d));
    sm0 += __shfl_xor(sm0, d);
    sm1 += __shfl_xor(sm1, d);
    sq0 += __shfl_xor(sq0, d);
    sq1 += __shfl_xor(sq1, d);
  }
  const float mu0 = sm0 * (1.f / 2048.f), mu1 = sm1 * (1.f / 2048.f);
  const float sg0 = sqrtf(fmaxf(sq0 * (1.f / 2048.f) - mu0 * mu0, 0.f)) + 1e-9f;
  const float sg1 = sqrtf(fmaxf(sq1 * (1.f / 2048.f) - mu1 * mu1, 0.f)) + 1e-9f;

  auto cnt2 = [&](float t0, float t1, int& o0, int& o1) {
    int cc = 0;
    #pragma unroll
    for (int t = 0; t < 32; t++)
      cc += (k0v[t] >= t0 ? 1 : 0) + (k1v[t] >= t1 ? 0x10000 : 0);
    #pragma unroll
    for (int d = 1; d < 64; d <<= 1) cc += __shfl_xor(cc, d);
    o0 = cc & 0xffff; o1 = cc >> 16;
  };

  float lo0 = mu0 + sg0, lo1 = mu1 + sg1;
  float hi0 = mx0 + fabsf(mx0) * 1e-6f + 1e-20f;
  float hi1 = mx1 + fabsf(mx1) * 1e-6f + 1e-20f;
  int c0n, c1n;
  cnt2(lo0, lo1, c0n, c1n);
  if ((c0n < topk) || (c1n < topk)) {            // rare bracket repair
    if (c0n < topk) lo0 = mu0;
    if (c1n < topk) lo1 = mu1;
    int c0b, c1b;
    cnt2(lo0, lo1, c0b, c1b);
    if (c0b < topk) lo0 = mu0 - 20.f * sg0;      // Chebyshev-certain
    if (c1b < topk) lo1 = mu1 - 20.f * sg1;
  }
  #pragma unroll 1
  for (int it = 0; it < 10; it++) {
    float m0 = 0.5f * (lo0 + hi0), m1 = 0.5f * (lo1 + hi1);
    cnt2(m0, m1, c0n, c1n);
    if (c0n >= topk) lo0 = m0; else hi0 = m0;
    if (c1n >= topk) lo1 = m1; else hi1 = m1;
  }
  const float C0 = hi0 + 2.f * DELTA, L0 = lo0 - 2.f * DELTA;
  const float C1 = hi1 + 2.f * DELTA, L1 = lo1 - 2.f * DELTA;

  // scratch aliased into each row's S span (keys fully in regs)
  char* sb0 = (char*)S0;
  char* sb1 = (char*)S1;
  float* Pl0 = (float*)sb0;          int* Jl0 = (int*)(sb0 + 512);
  float* Sx0 = (float*)(sb0 + 1024); int* Jc0 = (int*)(sb0 + 1280);
  float* Pl1 = (float*)sb1;          int* Jl1 = (int*)(sb1 + 512);
  float* Sx1 = (float*)(sb1 + 1024); int* Jc1 = (int*)(sb1 + 1280);
  asm volatile("" ::: "memory");
  const unsigned long long lmlt = (1ull << lane) - 1ull;

  int base0 = 0, base1 = 0, mc0 = 0, mc1 = 0;
  #pragma unroll
  for (int t = 0; t < 32; t++) {
    const int j = 2 * lane + 128 * (t >> 1) + (t & 1);
    bool dk0 = k0v[t] >= C0;
    bool cd0 = (k0v[t] >= L0) && !dk0;
    unsigned long long mk = __ballot(dk0);
    if (dk0) { int pos = base0 + __popcll(mk & lmlt); Pl0[pos] = k0v[t]; Jl0[pos] = j; }
    base0 += __popcll(mk);
    mk = __ballot(cd0);
    if (cd0) { int pos = mc0 + __popcll(mk & lmlt); if (pos < 64) Jc0[pos] = j; }
    mc0 += __popcll(mk);
    bool dk1 = k1v[t] >= C1;
    bool cd1 = (k1v[t] >= L1) && !dk1;
    mk = __ballot(dk1);
    if (dk1) { int pos = base1 + __popcll(mk & lmlt); Pl1[pos] = k1v[t]; Jl1[pos] = j; }
    base1 += __popcll(mk);
    mk = __ballot(cd1);
    if (cd1) { int pos = mc1 + __popcll(mk & lmlt); if (pos < 64) Jc1[pos] = j; }
    mc1 += __popcll(mk);
  }
  if (mc0 > 64) mc0 = 64;
  if (mc1 > 64) mc1 = 64;
  asm volatile("" ::: "memory");

  // exact recompute of candidates (f64 accum from ~f32-exact q32/k32)
  const double qv0 = (double)q32[((size_t)bh * Nn + ii0) * 64 + lane];
  const double qv1 = (double)q32[((size_t)bh * Nn + ii1) * 64 + lane];
  const int mcx = mc0 > mc1 ? mc0 : mc1;
  #pragma unroll 1
  for (int c2 = 0; c2 < mcx; c2++) {
    double t0 = 0.0, t1 = 0.0;
    if (c2 < mc0) {
      int j = Jc0[c2];
      int ridx = ii0 - j + 256; ridx = ridx < 0 ? 0 : (ridx > 255 ? 255 : ridx);
      t0 = qv0 * ((double)k32[((size_t)bh * Nn + j) * 64 + lane] +
                  (double)rel32[ridx * 64 + lane]);
    }
    if (c2 < mc1) {
      int j = Jc1[c2];
      int ridx = ii1 - j + 256; ridx = ridx < 0 ? 0 : (ridx > 255 ? 255 : ridx);
      t1 = qv1 * ((double)k32[((size_t)bh * Nn + j) * 64 + lane] +
                  (double)rel32[ridx * 64 + lane]);
    }
    #pragma unroll
    for (int d = 1; d < 64; d <<= 1) {
      t0 += __shfl_xor(t0, d);
      t1 += __shfl_xor(t1, d);
    }
    if (lane == 0) {
      if (c2 < mc0) Sx0[c2] = (float)t0;
      if (c2 < mc1) Sx1[c2] = (float)t1;
    }
  }
  asm volatile("" ::: "memory");

  // rank by exact score; numpy tie semantics (== vk kept)
  const int need0 = topk - base0, need1 = topk - base1;
  float myx0 = (lane < mc0) ? Sx0[lane] : -3.0e38f;
  float myx1 = (lane < mc1) ? Sx1[lane] : -3.0e38f;
  int rank0 = 0, rank1 = 0;
  #pragma unroll 1
  for (int c2 = 0; c2 < mcx; c2++) {
    if (c2 < mc0) { float o = Sx0[c2]; rank0 += (o > myx0 || (o == myx0 && c2 < lane)) ? 1 : 0; }
    if (c2 < mc1) { float o = Sx1[c2]; rank1 += (o > myx1 || (o == myx1 && c2 < lane)) ? 1 : 0; }
  }
  unsigned long long bm0 = __ballot((lane < mc0) && (rank0 == need0 - 1));
  unsigned long long bm1 = __ballot((lane < mc1) && (rank1 == need1 - 1));
  float vk0 = bm0 ? __shfl(myx0, (int)__ffsll(bm0) - 1) : 3.0e38f;
  float vk1 = bm1 ? __shfl(myx1, (int)__ffsll(bm1) - 1) : 3.0e38f;
  bool ck0 = (lane < mc0) && ((rank0 < need0) || (myx0 == vk0));
  bool ck1 = (lane < mc1) && ((rank1 < need1) || (myx1 == vk1));
  unsigned long long km0 = __ballot(ck0), km1 = __ballot(ck1);
  if (ck0) { int pos = base0 + __popcll(km0 & lmlt); Pl0[pos] = myx0; Jl0[pos] = Jc0[lane]; }
  if (ck1) { int pos = base1 + __popcll(km1 & lmlt); Pl1[pos] = myx1; Jl1[pos] = Jc1[lane]; }
  const int nk0 = base0 + __popcll(km0);
  const int nk1 = base1 + __popcll(km1);
  asm volatile("" ::: "memory");

  // exp + denom (nk can exceed 64 on ties)
  float ps0 = 0.f, ps1 = 0.f;
  #pragma unroll 1
  for (int t = lane; t < nk0; t += 64) { float p = __expf(Pl0[t] - mx0); Pl0[t] = p; ps0 += p; }
  #pragma unroll 1
  for (int t = lane; t < nk1; t += 64) { float p = __expf(Pl1[t] - mx1); Pl1[t] = p; ps1 += p; }
  #pragma unroll
  for (int d = 1; d < 64; d <<= 1) {
    ps0 += __shfl_xor(ps0, d);
    ps1 += __shfl_xor(ps1, d);
  }
  const float coef0 = gating[(size_t)b * Nn + ii0] / ps0;
  const float coef1 = gating[(size_t)b * Nn + ii1] / ps1;
  asm volatile("" ::: "memory");

  // PV gather, both rows interleaved (f16 v)
  const _Float16* vbp = vh + (size_t)bh * Nn * 64 + lane;
  float a00 = 0.f, a01 = 0.f, a10 = 0.f, a11 = 0.f;
  const int nmin = (nk0 < nk1 ? nk0 : nk1) & ~1;
  #pragma unroll 1
  for (int t = 0; t < nmin; t += 2) {
    float p00 = Pl0[t], p01 = Pl0[t + 1]; int j00 = Jl0[t], j01 = Jl0[t + 1];
    float p10 = Pl1[t], p11 = Pl1[t + 1]; int j10 = Jl1[t], j11 = Jl1[t + 1];
    a00 += p00 * (float)vbp[(size_t)j00 * 64];
    a01 += p01 * (float)vbp[(size_t)j01 * 64];
    a10 += p10 * (float)vbp[(size_t)j10 * 64];
    a11 += p11 * (float)vbp[(size_t)j11 * 64];
  }
  #pragma unroll 1
  for (int t = nmin; t < nk0; t++) a00 += Pl0[t] * (float)vbp[(size_t)Jl0[t] * 64];
  #pragma unroll 1
  for (int t = nmin; t < nk1; t++) a10 += Pl1[t] * (float)vbp[(size_t)Jl1[t] * 64];
  inner[((size_t)b * Nn + ii0) * 1024 + h * 64 + lane] = (a00 + a01) * coef0;
  inner[((size_t)b * Nn + ii1) * 1024 + h * 64 + lane] = (a10 + a11) * coef1;
}

extern "C" void kernel_launch(void* const* d_in, const int* in_sizes, int n_in,
                              void* d_out, int out_size, void* d_ws, size_t ws_size,
                              hipStream_t stream) {
  const float* x      = (const float*)d_in[0];
  const float* gating = (const float*)d_in[1];
  const float* Wq     = (const float*)d_in[2];
  const float* bq     = (const float*)d_in[3];
  const float* Wkv    = (const float*)d_in[4];
  const float* bkv    = (const float*)d_in[5];
  const float* Wo     = (const float*)d_in[6];
  const float* bo     = (const float*)d_in[7];
  const float* rel    = (const float*)d_in[8];
  const int*   topk   = (const int*)d_in[10];
  float* out = (float*)d_out;

  char* ws = (char*)d_ws;
  size_t off = 0;
  auto alloc = [&](size_t bytes) -> void* {
    void* p = ws + off; off += (bytes + 255) & ~(size_t)255; return p;
  };
  unsigned short* Wqt0 = (unsigned short*)alloc(1024ull * 1024 * 2);
  unsigned short* Wqt1 = (unsigned short*)alloc(1024ull * 1024 * 2);
  unsigned short* Wqt2 = (unsigned short*)alloc(1024ull * 1024 * 2);
  unsigned short* Wkt0 = (unsigned short*)alloc(2048ull * 1024 * 2);
  unsigned short* Wkt1 = (unsigned short*)alloc(2048ull * 1024 * 2);
  unsigned short* Wkt2 = (unsigned short*)alloc(2048ull * 1024 * 2);
  unsigned short* Wot0 = (unsigned short*)alloc(1024ull * 1024 * 2);
  unsigned short* Wot1 = (unsigned short*)alloc(1024ull * 1024 * 2);
  unsigned short* relbf = (unsigned short*)alloc(256ull * 64 * 2);
  float* q32 = (float*)alloc((size_t)BHn * Nn * 64 * 4);
  float* k32 = (float*)alloc((size_t)BHn * Nn * 64 * 4);
  unsigned short* qhb = (unsigned short*)alloc((size_t)BHn * Nn * 64 * 2);
  unsigned short* qmb = (unsigned short*)alloc((size_t)BHn * Nn * 64 * 2);
  unsigned short* khb = (unsigned short*)alloc((size_t)BHn * Nn * 64 * 2);
  unsigned short* kmb = (unsigned short*)alloc((size_t)BHn * Nn * 64 * 2);
  _Float16* vhb = (_Float16*)alloc((size_t)BHn * Nn * 64 * 2);
  float* inner = (float*)alloc((size_t)Bn * Nn * 1024 * 4);
  if (off > ws_size) return;  // workspace too small -> loud validation fail

  size_t shmem = 65536 + 16384;  // 81920 B -> 2 WG/CU
  (void)hipFuncSetAttribute((const void*)attn_k,
                            hipFuncAttributeMaxDynamicSharedMemorySize, (int)shmem);

  transpose_split3<<<dim3(32, 32), 256, 0, stream>>>(Wq, Wqt0, Wqt1, Wqt2, 1024, 1024);
  transpose_split3<<<dim3(64, 32), 256, 0, stream>>>(Wkv, Wkt0, Wkt1, Wkt2, 1024, 2048);
  transpose_split2<<<dim3(32, 32), 256, 0, stream>>>(Wo, Wot0, Wot1, 1024, 1024);
  convert_bf16<<<dim3(64), 256, 0, stream>>>(rel, relbf, 256 * 64);

  // q = (x@Wq + bq) * 1/8  (scale folded; exact pow2)
  gemm_qkv<<<dim3(8, 64), 256, 0, stream>>>(x, Wqt0, Wqt1, Wqt2, bq,
      q32, qhb, qmb, vhb, 1024, 0.125f);
  // k | v = x@Wkv + bkv
  gemm_qkv<<<dim3(16, 64), 256, 0, stream>>>(x, Wkt0, Wkt1, Wkt2, bkv,
      k32, khb, kmb, vhb, 1024, 1.0f);

  attn_k<<<dim3(128, 64), 512, shmem, stream>>>(qhb, qmb, khb, kmb, vhb,
      q32, k32, relbf, rel, gating, topk, inner);

  // out = inner@Wo + bo
  gemm_out<<<dim3(8, 64), 256, 0, stream>>>(inner, Wot0, Wot1, bo,
      out, 1024, 1024);
}

// Round 6
// 1174.082 us; speedup vs baseline: 1.1057x; 1.1057x over previous
//
#include <hip/hip_runtime.h>
#include <stdint.h>

// Sparse top-k attention (B=4,N=2048,H=16,DH=64, topk=64).
// Selection matches numpy f32: q32/k32 ~f32-exact (6-term 3-word-split MFMA);
// bulk scores 3-term 2-word MFMA stored f16 (|err| <= DELTA); 10-step value
// bisection; boundary candidates recomputed from q32/k32 (f64 accum) and
// ranked exactly with numpy tie semantics. v in f16.
// attn_k: 1024 thr / 16 waves, ONE row per wave -> 2 WG/CU = 100% occupancy.

typedef __attribute__((ext_vector_type(8))) short short8;
typedef __attribute__((ext_vector_type(4))) float floatx4;

#define Bn   4
#define Nn   2048
#define Hn   16
#define BHn  (Bn*Hn)
#define DELTA 0.00125f

__device__ __forceinline__ float bf2f(unsigned short u) {
  union { unsigned int i; float f; } v; v.i = ((unsigned int)u) << 16; return v.f;
}
__device__ __forceinline__ unsigned short f2bf(float f) {
  union { float f; unsigned int i; } v; v.f = f;
  unsigned int r = v.i + 0x7fffu + ((v.i >> 16) & 1u);
  return (unsigned short)(r >> 16);
}
__device__ __forceinline__ floatx4 mfma16(short8 a, short8 b, floatx4 c) {
  return __builtin_amdgcn_mfma_f32_16x16x32_bf16(a, b, c, 0, 0, 0);
}
__device__ __forceinline__ void split2(float x, unsigned short& h, unsigned short& m) {
  h = f2bf(x);
  m = f2bf(x - bf2f(h));
}
__device__ __forceinline__ void split3(float x, unsigned short& h, unsigned short& m, unsigned short& l) {
  h = f2bf(x);
  float r = x - bf2f(h);
  m = f2bf(r);
  l = f2bf(r - bf2f(m));
}

// ---- W[K][N] f32 -> T0/T1/T2[N][K] bf16 3-word split
__global__ __launch_bounds__(256)
void transpose_split3(const float* __restrict__ W,
                      unsigned short* __restrict__ T0,
                      unsigned short* __restrict__ T1,
                      unsigned short* __restrict__ T2,
                      int K, int Ncols)
{
  __shared__ float tile[32][33];
  int k0 = blockIdx.y * 32, n0 = blockIdx.x * 32;
  int tx = threadIdx.x & 31, ty = threadIdx.x >> 5;
  for (int s = 0; s < 32; s += 8)
    tile[ty + s][tx] = W[(size_t)(k0 + ty + s) * Ncols + n0 + tx];
  __syncthreads();
  for (int s = 0; s < 32; s += 8) {
    float x = tile[tx][ty + s];
    unsigned short h, m, l;
    split3(x, h, m, l);
    size_t o = (size_t)(n0 + ty + s) * K + k0 + tx;
    T0[o] = h; T1[o] = m; T2[o] = l;
  }
}

// ---- W[K][N] f32 -> T0/T1[N][K] bf16 2-word split
__global__ __launch_bounds__(256)
void transpose_split2(const float* __restrict__ W,
                      unsigned short* __restrict__ T0,
                      unsigned short* __restrict__ T1,
                      int K, int Ncols)
{
  __shared__ float tile[32][33];
  int k0 = blockIdx.y * 32, n0 = blockIdx.x * 32;
  int tx = threadIdx.x & 31, ty = threadIdx.x >> 5;
  for (int s = 0; s < 32; s += 8)
    tile[ty + s][tx] = W[(size_t)(k0 + ty + s) * Ncols + n0 + tx];
  __syncthreads();
  for (int s = 0; s < 32; s += 8) {
    float x = tile[tx][ty + s];
    unsigned short h, m;
    split2(x, h, m);
    size_t o = (size_t)(n0 + ty + s) * K + k0 + tx;
    T0[o] = h; T1[o] = m;
  }
}

__global__ __launch_bounds__(256)
void convert_bf16(const float* __restrict__ in, unsigned short* __restrict__ outp, int n) {
  int i = blockIdx.x * 256 + threadIdx.x;
  if (i < n) outp[i] = f2bf(in[i]);
}

// ---- QKV GEMM: A(f32) split3 on the fly, B 3-word. q/k tiles: 6 MFMA terms
// (~f32-exact), outputs f32 + 2-word bf16. Pure-V tiles (n0>=1024): 3 terms,
// f16 output.
__global__ __launch_bounds__(256)
void gemm_qkv(const float* __restrict__ A,
              const unsigned short* __restrict__ B0,
              const unsigned short* __restrict__ B1,
              const unsigned short* __restrict__ B2,
              const float* __restrict__ bias,
              float* __restrict__ O32,
              unsigned short* __restrict__ Oh,
              unsigned short* __restrict__ Om,
              _Float16* __restrict__ Vh,
              int K, float scale)
{
  __shared__ unsigned short lA[3][128 * 40];
  __shared__ unsigned short lB[3][128 * 40];
  const int tid = threadIdx.x;
  const int lane = tid & 63;
  const int m0 = blockIdx.y * 128, n0 = blockIdx.x * 128;
  const bool vblk = (n0 >= 1024);
  const int wid = tid >> 6, wm = wid >> 1, wn = wid & 1;
  const int fr = lane & 15, fq = lane >> 4;
  floatx4 acc[4][4] = {};

  for (int k0 = 0; k0 < K; k0 += 32) {
    __syncthreads();
    #pragma unroll
    for (int p = 0; p < 2; p++) {
      int c = tid + p * 256;
      int row = c >> 2, kc = (c & 3) * 8;
      size_t go = (size_t)(m0 + row) * K + k0 + kc;
      float4 v0 = *(const float4*)&A[go];
      float4 v1 = *(const float4*)&A[go + 4];
      union { unsigned short u[8]; uint4 q; } hh, mm, ll;
      float xs[8] = {v0.x, v0.y, v0.z, v0.w, v1.x, v1.y, v1.z, v1.w};
      #pragma unroll
      for (int e = 0; e < 8; e++) split3(xs[e], hh.u[e], mm.u[e], ll.u[e]);
      *(uint4*)&lA[0][row * 40 + kc] = hh.q;
      *(uint4*)&lA[1][row * 40 + kc] = mm.q;
      size_t bo = (size_t)(n0 + row) * K + k0 + kc;
      *(uint4*)&lB[0][row * 40 + kc] = *(const uint4*)&B0[bo];
      *(uint4*)&lB[1][row * 40 + kc] = *(const uint4*)&B1[bo];
      if (!vblk) {
        *(uint4*)&lA[2][row * 40 + kc] = ll.q;
        *(uint4*)&lB[2][row * 40 + kc] = *(const uint4*)&B2[bo];
      }
    }
    __syncthreads();
    short8 af0[4], af1[4], af2[4], bf0[4], bf1[4], bf2v[4];
    #pragma unroll
    for (int t = 0; t < 4; t++) {
      int ao = (wm * 64 + t * 16 + fr) * 40 + 8 * fq;
      int bo2 = (wn * 64 + t * 16 + fr) * 40 + 8 * fq;
      af0[t] = *(const short8*)&lA[0][ao];
      af1[t] = *(const short8*)&lA[1][ao];
      bf0[t] = *(const short8*)&lB[0][bo2];
      bf1[t] = *(const short8*)&lB[1][bo2];
      if (!vblk) {
        af2[t] = *(const short8*)&lA[2][ao];
        bf2v[t] = *(const short8*)&lB[2][bo2];
      }
    }
    #pragma unroll
    for (int mi = 0; mi < 4; mi++)
      #pragma unroll
      for (int ni = 0; ni < 4; ni++) {
        acc[mi][ni] = mfma16(af0[mi], bf0[ni], acc[mi][ni]);
        acc[mi][ni] = mfma16(af0[mi], bf1[ni], acc[mi][ni]);
        acc[mi][ni] = mfma16(af1[mi], bf0[ni], acc[mi][ni]);
        if (!vblk) {
          acc[mi][ni] = mfma16(af1[mi], bf1[ni], acc[mi][ni]);
          acc[mi][ni] = mfma16(af0[mi], bf2v[ni], acc[mi][ni]);
          acc[mi][ni] = mfma16(af2[mi], bf0[ni], acc[mi][ni]);
        }
      }
  }
  // C/D frag: row=(lane>>4)*4+rg, col=lane&15
  #pragma unroll
  for (int mi = 0; mi < 4; mi++)
    #pragma unroll
    for (int ni = 0; ni < 4; ni++) {
      int nl = n0 + wn * 64 + ni * 16 + fr;
      float bv = bias[nl];
      #pragma unroll
      for (int rg = 0; rg < 4; rg++) {
        int ml = m0 + wm * 64 + mi * 16 + fq * 4 + rg;
        float val = (acc[mi][ni][rg] + bv) * scale;
        int bb = ml >> 11, ii = ml & 2047;
        int hh2 = (nl & 1023) >> 6, dd = nl & 63;
        size_t idx = (((size_t)bb * Hn + hh2) * Nn + ii) * 64 + dd;
        if (!vblk) {
          O32[idx] = val;
          unsigned short h, m;
          split2(val, h, m);
          Oh[idx] = h; Om[idx] = m;
        } else {
          Vh[idx] = (_Float16)val;
        }
      }
    }
}

// ---- output GEMM: A f32 split2, B 2-word, 3 terms, f32 out.
__global__ __launch_bounds__(256)
void gemm_out(const float* __restrict__ A,
              const unsigned short* __restrict__ B0,
              const unsigned short* __restrict__ B1,
              const float* __restrict__ bias,
              float* __restrict__ O32,
              int Ncols, int K)
{
  __shared__ unsigned short lA[2][128 * 40];
  __shared__ unsigned short lB[2][128 * 40];
  const int tid = threadIdx.x;
  const int lane = tid & 63;
  const int m0 = blockIdx.y * 128, n0 = blockIdx.x * 128;
  const int wid = tid >> 6, wm = wid >> 1, wn = wid & 1;
  const int fr = lane & 15, fq = lane >> 4;
  floatx4 acc[4][4] = {};

  for (int k0 = 0; k0 < K; k0 += 32) {
    __syncthreads();
    #pragma unroll
    for (int p = 0; p < 2; p++) {
      int c = tid + p * 256;
      int row = c >> 2, kc = (c & 3) * 8;
      size_t go = (size_t)(m0 + row) * K + k0 + kc;
      float4 v0 = *(const float4*)&A[go];
      float4 v1 = *(const float4*)&A[go + 4];
      union { unsigned short u[8]; uint4 q; } hh, mm;
      float xs[8] = {v0.x, v0.y, v0.z, v0.w, v1.x, v1.y, v1.z, v1.w};
      #pragma unroll
      for (int e = 0; e < 8; e++) split2(xs[e], hh.u[e], mm.u[e]);
      *(uint4*)&lA[0][row * 40 + kc] = hh.q;
      *(uint4*)&lA[1][row * 40 + kc] = mm.q;
      size_t bo = (size_t)(n0 + row) * K + k0 + kc;
      *(uint4*)&lB[0][row * 40 + kc] = *(const uint4*)&B0[bo];
      *(uint4*)&lB[1][row * 40 + kc] = *(const uint4*)&B1[bo];
    }
    __syncthreads();
    short8 af[2][4], bfr[2][4];
    #pragma unroll
    for (int s = 0; s < 2; s++)
      #pragma unroll
      for (int t = 0; t < 4; t++) {
        af[s][t]  = *(const short8*)&lA[s][(wm * 64 + t * 16 + fr) * 40 + 8 * fq];
        bfr[s][t] = *(const short8*)&lB[s][(wn * 64 + t * 16 + fr) * 40 + 8 * fq];
      }
    #pragma unroll
    for (int mi = 0; mi < 4; mi++)
      #pragma unroll
      for (int ni = 0; ni < 4; ni++) {
        acc[mi][ni] = mfma16(af[0][mi], bfr[0][ni], acc[mi][ni]);
        acc[mi][ni] = mfma16(af[0][mi], bfr[1][ni], acc[mi][ni]);
        acc[mi][ni] = mfma16(af[1][mi], bfr[0][ni], acc[mi][ni]);
      }
  }
  #pragma unroll
  for (int mi = 0; mi < 4; mi++)
    #pragma unroll
    for (int ni = 0; ni < 4; ni++) {
      int nl = n0 + wn * 64 + ni * 16 + fr;
      float bv = bias[nl];
      #pragma unroll
      for (int rg = 0; rg < 4; rg++) {
        int ml = m0 + wm * 64 + mi * 16 + fq * 4 + rg;
        O32[(size_t)ml * Ncols + nl] = acc[mi][ni][rg] + bv;
      }
    }
}

// ---- attention: one WG (16 waves / 1024 thr) = 16 query rows; wave w owns
// row w. QK^T MFMA by waves 0-7 (round-5 mapping); all waves stage.
// S/qE column-swizzled by (row>>2)<<4; Kt chunk-swizzled by row&7.
__global__ __launch_bounds__(1024, 8)
void attn_k(const unsigned short* __restrict__ qh,
            const unsigned short* __restrict__ qm,
            const unsigned short* __restrict__ kh,
            const unsigned short* __restrict__ km,
            const _Float16* __restrict__ vh,
            const float* __restrict__ q32,
            const float* __restrict__ k32,
            const unsigned short* __restrict__ relbf,
            const float* __restrict__ rel32,
            const float* __restrict__ gating,
            const int* __restrict__ topkp,
            float* __restrict__ inner)
{
  extern __shared__ char smem[];
  _Float16* S = (_Float16*)smem;                          // [16][2048] 65536B
  unsigned short* KtH = (unsigned short*)(smem + 65536);  // [64][64] 8192B
  unsigned short* KtM = KtH + 4096;                       // [64][64] 8192B
  _Float16* qE = (_Float16*)KtH;                          // [16][256] reuse

  const int ib = blockIdx.x, bh = blockIdx.y;
  const int i0 = ib * 16;
  const int b = bh >> 4, h = bh & 15;
  const int tid = threadIdx.x;
  const int lane = tid & 63, w = tid >> 6;      // w in [0,16)
  const int fr = lane & 15, fq = lane >> 4;
  const int topk = topkp[0];

  // q A-fragments, 2-word
  const size_t qoff = ((size_t)bh * Nn + i0) * 64;
  const size_t qf = qoff + (size_t)fr * 64 + 8 * fq;
  const short8 aqh0 = *(const short8*)&qh[qf];
  const short8 aqh1 = *(const short8*)&qh[qf + 32];
  const short8 aqm0 = *(const short8*)&qm[qf];
  const short8 aqm1 = *(const short8*)&qm[qf + 32];

  // QK^T: 32 tiles of 64 cols; MFMA by waves 0-3 (even tiles) / 4-7 (odd)
  for (int jt = 0; jt < 32; jt++) {
    __syncthreads();
    {
      int sel = tid >> 9;                 // 0: KtH, 1: KtM
      int row = (tid >> 3) & 63, ch = tid & 7;
      int dst = row * 64 + ((ch ^ (row & 7)) * 8);   // chunk swizzle
      size_t g = ((size_t)bh * Nn + jt * 64 + row) * 64 + ch * 8;
      unsigned short* T = sel ? KtM : KtH;
      const unsigned short* src = sel ? km : kh;
      *(uint4*)&T[dst] = *(const uint4*)&src[g];
    }
    __syncthreads();
    if (w < 8 && ((jt & 1) == (w >> 2))) {
      int wc = w & 3;
      int row16 = wc * 16 + fr, r7 = fr & 7;
      int b0 = row16 * 64 + ((fq ^ r7) * 8);
      int b1 = row16 * 64 + (((fq + 4) ^ r7) * 8);
      short8 kh0 = *(const short8*)&KtH[b0];
      short8 kh1 = *(const short8*)&KtH[b1];
      short8 km0 = *(const short8*)&KtM[b0];
      short8 km1 = *(const short8*)&KtM[b1];
      floatx4 c = {};
      c = mfma16(aqh0, kh0, c); c = mfma16(aqh1, kh1, c);
      c = mfma16(aqh0, km0, c); c = mfma16(aqh1, km1, c);
      c = mfma16(aqm0, kh0, c); c = mfma16(aqm1, kh1, c);
      int colsw = jt * 64 + ((wc ^ fq) * 16) + fr;   // col ^ ((row>>2)<<4)
      #pragma unroll
      for (int rg = 0; rg < 4; rg++)
        S[(fq * 4 + rg) * 2048 + colsw] = (_Float16)c[rg];
    }
  }
  __syncthreads();

  // qE[i_local][r] = q_i . rel_r : wave w computes strip w (16 rel rows)
  {
    size_t rf = (size_t)(w * 16 + fr) * 64 + 8 * fq;
    short8 rb0 = *(const short8*)&relbf[rf];
    short8 rb1 = *(const short8*)&relbf[rf + 32];
    floatx4 c = {};
    c = mfma16(aqh0, rb0, c); c = mfma16(aqh1, rb1, c);
    c = mfma16(aqm0, rb0, c); c = mfma16(aqm1, rb1, c);
    int colsw = ((w ^ fq) * 16) + fr;
    #pragma unroll
    for (int rg = 0; rg < 4; rg++)
      qE[(fq * 4 + rg) * 256 + colsw] = (_Float16)c[rg];
  }
  __syncthreads();

  // ---- single-row selection + softmax + PV (wave w owns row w)
  const int r = w;
  const int i = i0 + r;
  const int X = (r >> 2) << 4;
  _Float16* S0 = S + r * 2048;
  const _Float16* qE0 = qE + r * 256;
  const float cA = (float)qE0[255 ^ X], cC = (float)qE0[X];
  const int swl = (2 * lane) ^ X;

  float key[32];
  float mx = -3.0e38f, sm = 0.f, sq = 0.f;
  #pragma unroll
  for (int e = 0; e < 16; e++) {
    const int jb = 128 * e;
    union { unsigned int u; _Float16 hx[2]; } u0;
    u0.u = *(const unsigned int*)&S0[jb + swl];
    const int j0 = jb + 2 * lane;
    float e0, e1;
    if (jb + 127 <= i) { e0 = cA; e1 = cA; }
    else if (jb >= i + 256) { e0 = cC; e1 = cC; }
    else {
      int c0 = i - j0 + 256; c0 = c0 < 0 ? 0 : (c0 > 255 ? 255 : c0);
      int c1 = i - j0 + 255; c1 = c1 < 0 ? 0 : (c1 > 255 ? 255 : c1);
      e0 = (float)qE0[c0 ^ X]; e1 = (float)qE0[c1 ^ X];
    }
    float a0 = (float)u0.hx[0] + e0, a1 = (float)u0.hx[1] + e1;
    key[2 * e] = a0; key[2 * e + 1] = a1;
    mx = fmaxf(mx, fmaxf(a0, a1));
    sm += a0 + a1;
    sq = fmaf(a0, a0, fmaf(a1, a1, sq));
  }
  #pragma unroll
  for (int d = 1; d < 64; d <<= 1) {
    mx = fmaxf(mx, __shfl_xor(mx, d));
    sm += __shfl_xor(sm, d);
    sq += __shfl_xor(sq, d);
  }
  const float mu = sm * (1.f / 2048.f);
  const float sg = sqrtf(fmaxf(sq * (1.f / 2048.f) - mu * mu, 0.f)) + 1e-9f;

  auto cntGE = [&](float u) -> int {
    int c = 0;
    #pragma unroll
    for (int t = 0; t < 32; t++) c += (key[t] >= u) ? 1 : 0;
    #pragma unroll
    for (int d = 1; d < 64; d <<= 1) c += __shfl_xor(c, d);
    return c;
  };

  float lo = mu + 1.6f * sg;
  float hi = mx + fabsf(mx) * 1e-6f + 1e-20f;
  if (cntGE(lo) < topk) {                   // rare bracket repair
    lo = mu;
    if (cntGE(lo) < topk) lo = mu - 20.f * sg;   // Chebyshev-certain
  }
  #pragma unroll 1
  for (int it = 0; it < 10; it++) {
    float mid = 0.5f * (lo + hi);
    if (cntGE(mid) >= topk) lo = mid; else hi = mid;
  }
  const float C = hi + 2.f * DELTA, L = lo - 2.f * DELTA;

  // scratch aliased into this row's S span (keys fully in regs)
  char* sb = (char*)S0;
  float* Pl = (float*)sb;          int* Jl = (int*)(sb + 512);
  float* Sx = (float*)(sb + 1024); int* Jc = (int*)(sb + 1280);
  asm volatile("" ::: "memory");
  const unsigned long long lmlt = (1ull << lane) - 1ull;

  int base = 0, mc = 0;
  #pragma unroll
  for (int t = 0; t < 32; t++) {
    const int j = 2 * lane + 128 * (t >> 1) + (t & 1);
    bool dk = key[t] >= C;
    bool cd = (key[t] >= L) && !dk;
    unsigned long long mk = __ballot(dk);
    if (dk) { int pos = base + __popcll(mk & lmlt); Pl[pos] = key[t]; Jl[pos] = j; }
    base += __popcll(mk);
    mk = __ballot(cd);
    if (cd) { int pos = mc + __popcll(mk & lmlt); if (pos < 64) Jc[pos] = j; }
    mc += __popcll(mk);
  }
  if (mc > 64) mc = 64;
  asm volatile("" ::: "memory");

  // exact recompute of candidates (f64 accum from ~f32-exact q32/k32)
  const double qv = (double)q32[((size_t)bh * Nn + i) * 64 + lane];
  #pragma unroll 1
  for (int c2 = 0; c2 < mc; c2++) {
    int j = Jc[c2];
    int ridx = i - j + 256; ridx = ridx < 0 ? 0 : (ridx > 255 ? 255 : ridx);
    double t = qv * ((double)k32[((size_t)bh * Nn + j) * 64 + lane] +
                     (double)rel32[ridx * 64 + lane]);
    #pragma unroll
    for (int d = 1; d < 64; d <<= 1) t += __shfl_xor(t, d);
    if (lane == 0) Sx[c2] = (float)t;
  }
  asm volatile("" ::: "memory");

  // rank by exact score; numpy tie semantics (== vk kept)
  const int need = topk - base;
  float myx = (lane < mc) ? Sx[lane] : -3.0e38f;
  int rank = 0;
  #pragma unroll 1
  for (int c2 = 0; c2 < mc; c2++) {
    float o = Sx[c2];
    rank += (o > myx || (o == myx && c2 < lane)) ? 1 : 0;
  }
  unsigned long long bm = __ballot((lane < mc) && (rank == need - 1));
  float vk = bm ? __shfl(myx, (int)__ffsll(bm) - 1) : 3.0e38f;
  bool ck = (lane < mc) && ((rank < need) || (myx == vk));
  unsigned long long km2 = __ballot(ck);
  if (ck) { int pos = base + __popcll(km2 & lmlt); Pl[pos] = myx; Jl[pos] = Jc[lane]; }
  const int nk = base + __popcll(km2);
  asm volatile("" ::: "memory");

  // exp + denom (nk can exceed 64 on ties)
  float ps = 0.f;
  #pragma unroll 1
  for (int t = lane; t < nk; t += 64) { float p = __expf(Pl[t] - mx); Pl[t] = p; ps += p; }
  #pragma unroll
  for (int d = 1; d < 64; d <<= 1) ps += __shfl_xor(ps, d);
  const float coef = gating[(size_t)b * Nn + i] / ps;
  asm volatile("" ::: "memory");

  // PV gather (f16 v), 4-deep ILP
  const _Float16* vbp = vh + (size_t)bh * Nn * 64 + lane;
  float a0 = 0.f, a1 = 0.f, a2 = 0.f, a3 = 0.f;
  int t4 = nk & ~3;
  #pragma unroll 1
  for (int t = 0; t < t4; t += 4) {
    float p0 = Pl[t], p1 = Pl[t + 1], p2 = Pl[t + 2], p3 = Pl[t + 3];
    int j0 = Jl[t], j1 = Jl[t + 1], j2 = Jl[t + 2], j3 = Jl[t + 3];
    a0 += p0 * (float)vbp[(size_t)j0 * 64];
    a1 += p1 * (float)vbp[(size_t)j1 * 64];
    a2 += p2 * (float)vbp[(size_t)j2 * 64];
    a3 += p3 * (float)vbp[(size_t)j3 * 64];
  }
  #pragma unroll 1
  for (int t = t4; t < nk; t++) a0 += Pl[t] * (float)vbp[(size_t)Jl[t] * 64];
  inner[((size_t)b * Nn + i) * 1024 + h * 64 + lane] = (a0 + a1 + a2 + a3) * coef;
}

extern "C" void kernel_launch(void* const* d_in, const int* in_sizes, int n_in,
                              void* d_out, int out_size, void* d_ws, size_t ws_size,
                              hipStream_t stream) {
  const float* x      = (const float*)d_in[0];
  const float* gating = (const float*)d_in[1];
  const float* Wq     = (const float*)d_in[2];
  const float* bq     = (const float*)d_in[3];
  const float* Wkv    = (const float*)d_in[4];
  const float* bkv    = (const float*)d_in[5];
  const float* Wo     = (const float*)d_in[6];
  const float* bo     = (const float*)d_in[7];
  const float* rel    = (const float*)d_in[8];
  const int*   topk   = (const int*)d_in[10];
  float* out = (float*)d_out;

  char* ws = (char*)d_ws;
  size_t off = 0;
  auto alloc = [&](size_t bytes) -> void* {
    void* p = ws + off; off += (bytes + 255) & ~(size_t)255; return p;
  };
  unsigned short* Wqt0 = (unsigned short*)alloc(1024ull * 1024 * 2);
  unsigned short* Wqt1 = (unsigned short*)alloc(1024ull * 1024 * 2);
  unsigned short* Wqt2 = (unsigned short*)alloc(1024ull * 1024 * 2);
  unsigned short* Wkt0 = (unsigned short*)alloc(2048ull * 1024 * 2);
  unsigned short* Wkt1 = (unsigned short*)alloc(2048ull * 1024 * 2);
  unsigned short* Wkt2 = (unsigned short*)alloc(2048ull * 1024 * 2);
  unsigned short* Wot0 = (unsigned short*)alloc(1024ull * 1024 * 2);
  unsigned short* Wot1 = (unsigned short*)alloc(1024ull * 1024 * 2);
  unsigned short* relbf = (unsigned short*)alloc(256ull * 64 * 2);
  float* q32 = (float*)alloc((size_t)BHn * Nn * 64 * 4);
  float* k32 = (float*)alloc((size_t)BHn * Nn * 64 * 4);
  unsigned short* qhb = (unsigned short*)alloc((size_t)BHn * Nn * 64 * 2);
  unsigned short* qmb = (unsigned short*)alloc((size_t)BHn * Nn * 64 * 2);
  unsigned short* khb = (unsigned short*)alloc((size_t)BHn * Nn * 64 * 2);
  unsigned short* kmb = (unsigned short*)alloc((size_t)BHn * Nn * 64 * 2);
  _Float16* vhb = (_Float16*)alloc((size_t)BHn * Nn * 64 * 2);
  float* inner = (float*)alloc((size_t)Bn * Nn * 1024 * 4);
  if (off > ws_size) return;  // workspace too small -> loud validation fail

  size_t shmem = 65536 + 16384;  // 81920 B -> 2 WG/CU (163840 = 160 KiB)
  (void)hipFuncSetAttribute((const void*)attn_k,
                            hipFuncAttributeMaxDynamicSharedMemorySize, (int)shmem);

  transpose_split3<<<dim3(32, 32), 256, 0, stream>>>(Wq, Wqt0, Wqt1, Wqt2, 1024, 1024);
  transpose_split3<<<dim3(64, 32), 256, 0, stream>>>(Wkv, Wkt0, Wkt1, Wkt2, 1024, 2048);
  transpose_split2<<<dim3(32, 32), 256, 0, stream>>>(Wo, Wot0, Wot1, 1024, 1024);
  convert_bf16<<<dim3(64), 256, 0, stream>>>(rel, relbf, 256 * 64);

  // q = (x@Wq + bq) * 1/8  (scale folded; exact pow2)
  gemm_qkv<<<dim3(8, 64), 256, 0, stream>>>(x, Wqt0, Wqt1, Wqt2, bq,
      q32, qhb, qmb, vhb, 1024, 0.125f);
  // k | v = x@Wkv + bkv
  gemm_qkv<<<dim3(16, 64), 256, 0, stream>>>(x, Wkt0, Wkt1, Wkt2, bkv,
      k32, khb, kmb, vhb, 1024, 1.0f);

  attn_k<<<dim3(128, 64), 1024, shmem, stream>>>(qhb, qmb, khb, kmb, vhb,
      q32, k32, relbf, rel, gating, topk, inner);

  // out = inner@Wo + bo
  gemm_out<<<dim3(8, 64), 256, 0, stream>>>(inner, Wot0, Wot1, bo,
      out, 1024, 1024);
}